// Round 10
// baseline (126.033 us; speedup 1.0000x reference)
//
#include <hip/hip_runtime.h>
#include <hip/hip_bf16.h>

typedef __attribute__((ext_vector_type(8))) _Float16 half8;
typedef __attribute__((ext_vector_type(2))) _Float16 hf2;
typedef __attribute__((ext_vector_type(2))) __fp16 fp16x2;
typedef __attribute__((ext_vector_type(4))) float f32x4;
typedef __attribute__((ext_vector_type(16))) float f32x16;

union UH8 {
  half8 v;
  unsigned long long q[2];
  unsigned int w[4];
};
union U32H {
  unsigned int u;
  hf2 h;
};

__device__ __forceinline__ unsigned int pkh(float lo, float hi) {
  union { fp16x2 h; unsigned int u; } c;
  c.h = __builtin_amdgcn_cvt_pkrtz(lo, hi);
  return c.u;
}

constexpr int S_LEN = 2048;
constexpr int D_DIM = 64;
constexpr int KVB   = 64;     // kv tile rows
constexpr int QB    = 128;    // q rows per block (4 waves x 32)
constexpr int NCHK  = 512;    // 16B chunks per 64x64 fp16 tile (8 KB)
constexpr int NT    = S_LEN / KVB;
constexpr float LOG2E = 1.4426950408889634f;
constexpr float INV_D_QTR = 0.35355339059327373f;  // 1 / 64^0.25
constexpr float THR_L2 = 6.0f;   // defer-max threshold (log2 units): P <= 2^6, fp16-safe

// Paired-row swizzled tile layout (both K and V^T):
//   logical (row in [0,64), chunk cc in [0,8), chunk = 8 consecutive fp16 cols)
//   physical chunk index = (row>>1)*16 + ((row&1)<<3) + (cc ^ ((row>>1)&7))
// Reads (lane rows 0..31 at fixed cc) and writes both hit each bank-quad with
// exactly 8 lanes => the b128 wave minimum; all accesses are single ds_*_b128.

__global__ __launch_bounds__(256) void attn_fwd(
    const float* __restrict__ Q, const float* __restrict__ K,
    const float* __restrict__ V, float* __restrict__ O)
{
  const int tid  = threadIdx.x;
  const int w    = tid >> 6;      // wave 0..3
  const int lane = tid & 63;
  const int q32  = lane & 31;     // q-row within wave tile / MFMA m,n index
  const int h    = lane >> 5;     // half-wave index

  // XCD-aware bijective swizzle (1024 = 8 x 128)
  const int bid = blockIdx.x;
  const int wg  = (bid & 7) * 128 + (bid >> 3);
  const int qb  = wg & 15;        // q-block within head
  const int bh  = wg >> 4;        // batch*head

  const int q0 = qb * QB;

  __shared__ UH8 KsB[2][NCHK];  // K tile [kv][d] fp16, paired-swizzled, dbuf
  __shared__ UH8 VtB[2][NCHK];  // V^T tile [d][kv] fp16, paired-swizzled, dbuf

  const size_t base = (size_t)bh * S_LEN * D_DIM;

  // ---- staging ownership ----
  const int kr  = tid >> 3;            // K row 0..31 (and +32)
  const int kcc = tid & 7;             // K chunk (8 fp16 = 8 f32 src) within row

  float4 ka0, kb0, ka1, kb1;
  float va[8], vb[8];

  auto PREF = [&](int tt) {
    const int kv0 = tt * KVB;
    const float* kp = K + base + (size_t)(kv0 + kr) * D_DIM + kcc * 8;
    ka0 = *(const float4*)kp;
    kb0 = *(const float4*)(kp + 4);
    const float* kp1 = kp + 32 * D_DIM;
    ka1 = *(const float4*)kp1;
    kb1 = *(const float4*)(kp1 + 4);
    const float* vp = V + base + (size_t)(kv0 + w * 16) * D_DIM + lane;
    #pragma unroll
    for (int p = 0; p < 8; ++p) {
      va[p] = vp[(2 * p) * D_DIM];
      vb[p] = vp[(2 * p + 1) * D_DIM];
    }
  };

  // write-side swizzle constants
  const int prk   = kr >> 1;
  const int kbase = prk * 16 + ((kr & 1) << 3) + (kcc ^ (prk & 7));
  const int prv   = lane >> 1;
  const int swv   = prv & 7;
  const int vbase = prv * 16 + ((lane & 1) << 3);
  const int vc0   = vbase + ((2 * w) ^ swv);
  const int vc1   = vbase + ((2 * w + 1) ^ swv);

  auto WRITE = [&](int b) {
    UH8 c0, c1;
    c0.w[0] = pkh(ka0.x, ka0.y); c0.w[1] = pkh(ka0.z, ka0.w);
    c0.w[2] = pkh(kb0.x, kb0.y); c0.w[3] = pkh(kb0.z, kb0.w);
    KsB[b][kbase] = c0;
    c1.w[0] = pkh(ka1.x, ka1.y); c1.w[1] = pkh(ka1.z, ka1.w);
    c1.w[2] = pkh(kb1.x, kb1.y); c1.w[3] = pkh(kb1.z, kb1.w);
    KsB[b][kbase + 256] = c1;
    UH8 d0, d1;
    #pragma unroll
    for (int j = 0; j < 4; ++j) {
      d0.w[j] = pkh(va[j], vb[j]);
      d1.w[j] = pkh(va[4 + j], vb[4 + j]);
    }
    VtB[b][vc0] = d0;
    VtB[b][vc1] = d1;
  };

  // read-side swizzle constants: row = (kvt|dt)*32 + q32, cc = 2s + h
  const int prq   = q32 >> 1;
  const int swq   = prq & 7;
  const int rbase = prq * 16 + ((q32 & 1) << 3);
  int eidx[4];
  #pragma unroll
  for (int s = 0; s < 4; ++s) eidx[s] = rbase + ((2 * s + h) ^ swq);

  // ---- Q fragments fp16, pre-scaled by LOG2E ----
  UH8 qf[4];
  {
    const float* qp = Q + base + (size_t)(q0 + w * 32 + q32) * D_DIM;
    #pragma unroll
    for (int s = 0; s < 4; ++s) {
      float4 a = *(const float4*)(qp + s * 16 + h * 8);
      float4 b = *(const float4*)(qp + s * 16 + h * 8 + 4);
      qf[s].w[0] = pkh(a.x * LOG2E, a.y * LOG2E);
      qf[s].w[1] = pkh(a.z * LOG2E, a.w * LOG2E);
      qf[s].w[2] = pkh(b.x * LOG2E, b.y * LOG2E);
      qf[s].w[3] = pkh(b.z * LOG2E, b.w * LOG2E);
    }
  }

  // O^T accum: oc[dt] reg r -> O[d = dt*32 + (r&3) + 8*(r>>2) + 4h][q = q32]
  f32x16 oc[2] = {
    {0,0,0,0,0,0,0,0,0,0,0,0,0,0,0,0},
    {0,0,0,0,0,0,0,0,0,0,0,0,0,0,0,0}
  };
  float mrow = -1e30f;   // running max in log2 units
  float lrow = 0.f;

  const U32H one = {0x3C003C00u};   // (1.0h, 1.0h)

  PREF(0);
  WRITE(0);

  for (int t = 0; t < NT; ++t) {
    const bool more = (t + 1 < NT);
    if (more) PREF(t + 1);     // loads in flight across the whole compute phase
    __syncthreads();
    const int cb = t & 1;
    const UH8* ksc = KsB[cb];
    const UH8* vtc = VtB[cb];

    // ---- swapped QK^T (32x32x16): sc[kvt] reg r = S[kv = kvt*32+(r&3)+8*(r>>2)+4h][q32]
    f32x16 sc[2];
    __builtin_amdgcn_s_setprio(1);
    #pragma unroll
    for (int kvt = 0; kvt < 2; ++kvt) {
      f32x16 acc = {0,0,0,0,0,0,0,0,0,0,0,0,0,0,0,0};
      #pragma unroll
      for (int s = 0; s < 4; ++s) {
        UH8 af;
        af.v = ksc[kvt * 256 + eidx[s]].v;   // single ds_read_b128
        acc = __builtin_amdgcn_mfma_f32_32x32x16_f16(af.v, qf[s].v, acc, 0, 0, 0);
      }
      sc[kvt] = acc;
    }
    __builtin_amdgcn_s_setprio(0);

    // ---- tile max, tree-form ----
    float u[8];
    #pragma unroll
    for (int j = 0; j < 8; ++j)
      u[j] = fmaxf(fmaxf(sc[0][j], sc[0][j + 8]), fmaxf(sc[1][j], sc[1][j + 8]));
    #pragma unroll
    for (int j = 0; j < 4; ++j) u[j] = fmaxf(u[j], u[j + 4]);
    float pm = fmaxf(fmaxf(u[0], u[2]), fmaxf(u[1], u[3]));
    pm = fmaxf(pm, __shfl_xor(pm, 32, 64));

    // ---- defer-max: rescale only when some row's max grew past THR_L2 ----
    if (__any(pm - mrow > THR_L2)) {
      const float mnew = fmaxf(mrow, pm);
      const float corr = __builtin_amdgcn_exp2f(mrow - mnew);
      #pragma unroll
      for (int dt = 0; dt < 2; ++dt)
        #pragma unroll
        for (int i = 0; i < 16; ++i)
          oc[dt][i] *= corr;
      lrow *= corr;
      mrow = mnew;
    }

    // ---- exp2 (scores already log2-scaled via Q-fold) ----
    #pragma unroll
    for (int kvt = 0; kvt < 2; ++kvt)
      #pragma unroll
      for (int i = 0; i < 16; ++i)
        sc[kvt][i] = __builtin_amdgcn_exp2f(sc[kvt][i] - mrow);

    // ---- swapped PV (32x32x16) + row-sum via fdot2 on the same fp16 packs ----
    float ps = 0.f;
    __builtin_amdgcn_s_setprio(1);
    #pragma unroll
    for (int s = 0; s < 4; ++s) {
      const int kvt = s >> 1;
      const int sr  = (s & 1) * 8;
      unsigned int LO0 = pkh(sc[kvt][sr + 0], sc[kvt][sr + 1]);
      unsigned int LO1 = pkh(sc[kvt][sr + 2], sc[kvt][sr + 3]);
      unsigned int HI0 = pkh(sc[kvt][sr + 4], sc[kvt][sr + 5]);
      unsigned int HI1 = pkh(sc[kvt][sr + 6], sc[kvt][sr + 7]);
      U32H c0 = {LO0}, c1 = {LO1}, c2 = {HI0}, c3 = {HI1};
      ps = __builtin_amdgcn_fdot2(c0.h, one.h, ps, false);
      ps = __builtin_amdgcn_fdot2(c1.h, one.h, ps, false);
      ps = __builtin_amdgcn_fdot2(c2.h, one.h, ps, false);
      ps = __builtin_amdgcn_fdot2(c3.h, one.h, ps, false);
      // v_permlane32_swap_b32 vdst, vsrc: vdst's HIGH 32 lanes <-> vsrc's LOW 32 lanes.
      asm("v_permlane32_swap_b32 %0, %1" : "+v"(LO0), "+v"(HI0));
      asm("v_permlane32_swap_b32 %0, %1" : "+v"(LO1), "+v"(HI1));
      UH8 pf;
      pf.w[0] = LO0;
      pf.w[1] = LO1;
      pf.w[2] = HI0;
      pf.w[3] = HI1;
      #pragma unroll
      for (int dt = 0; dt < 2; ++dt) {
        UH8 vf;
        vf.v = vtc[dt * 256 + eidx[s]].v;   // single ds_read_b128
        oc[dt] = __builtin_amdgcn_mfma_f32_32x32x16_f16(vf.v, pf.v, oc[dt], 0, 0, 0);
      }
    }
    __builtin_amdgcn_s_setprio(0);
    ps += __shfl_xor(ps, 32, 64);
    lrow += ps;

    if (more) WRITE(1 - cb);   // loads have had the whole compute phase to land
  }

  // ---- epilogue: O[q][d] = oc * (dim^-0.25 / l) ----
  const float inv = INV_D_QTR / lrow;
  float* orow = O + base + (size_t)(q0 + w * 32 + q32) * D_DIM;
  #pragma unroll
  for (int dt = 0; dt < 2; ++dt)
    #pragma unroll
    for (int r1 = 0; r1 < 4; ++r1) {
      f32x4 o = { oc[dt][4 * r1 + 0] * inv, oc[dt][4 * r1 + 1] * inv,
                  oc[dt][4 * r1 + 2] * inv, oc[dt][4 * r1 + 3] * inv };
      *(f32x4*)(orow + dt * 32 + 8 * r1 + 4 * h) = o;
    }
}

extern "C" void kernel_launch(void* const* d_in, const int* in_sizes, int n_in,
                              void* d_out, int out_size, void* d_ws, size_t ws_size,
                              hipStream_t stream) {
  const float* q = (const float*)d_in[0];
  const float* k = (const float*)d_in[1];
  const float* v = (const float*)d_in[2];
  float* o = (float*)d_out;
  const int nblocks = (S_LEN / QB) * 64;   // 16 q-blocks x 64 bh = 1024
  attn_fwd<<<dim3(nblocks), dim3(256), 0, stream>>>(q, k, v, o);
}